// Round 7
// baseline (1213.506 us; speedup 1.0000x reference)
//
#include <hip/hip_runtime.h>

#define DD 64
constexpr int N_P   = 100000;
constexpr int N_G   = 40000;
constexpr int NE    = 1600000;
constexpr int E_LBL = 500000;
constexpr int F_GO  = 1000;
constexpr int KSTEPS = 32;     // lin_go K padded to 1024 = 32 steps of 32
constexpr int NBG = N_G / 64;            // 625 update blocks (g)
constexpr int NBP = (N_P + 63) / 64;     // 1563 update blocks (p)
constexpr int ABG = (N_G + 3) / 4;       // 10000 aggregate blocks (g)
constexpr int ABP = (N_P + 3) / 4;       // 25000 aggregate blocks (p)

typedef __attribute__((ext_vector_type(8))) short bf16x8;
typedef __attribute__((ext_vector_type(4))) float f32x4;

// ---- fp32 -> bf16 hi/lo split (RNE) ----
__device__ __forceinline__ unsigned short f2bf_rne(float x) {
    unsigned u = __float_as_uint(x);
    u += 0x7fff + ((u >> 16) & 1);
    return (unsigned short)(u >> 16);
}
__device__ __forceinline__ float bf2f(unsigned short h) {
    return __uint_as_float((unsigned)h << 16);
}
struct BfPair { short h; short l; };
__device__ __forceinline__ BfPair split_bf(float x) {
    BfPair p;
    unsigned short hh = f2bf_rne(x);
    unsigned short ll = f2bf_rne(x - bf2f(hh));
    p.h = (short)hh; p.l = (short)ll;
    return p;
}
__device__ __forceinline__ void split8(float4 va, float4 vb, bf16x8 &ah, bf16x8 &al) {
    BfPair p0 = split_bf(va.x), p1 = split_bf(va.y), p2 = split_bf(va.z), p3 = split_bf(va.w);
    BfPair p4 = split_bf(vb.x), p5 = split_bf(vb.y), p6 = split_bf(vb.z), p7 = split_bf(vb.w);
    ah[0]=p0.h; ah[1]=p1.h; ah[2]=p2.h; ah[3]=p3.h;
    ah[4]=p4.h; ah[5]=p5.h; ah[6]=p6.h; ah[7]=p7.h;
    al[0]=p0.l; al[1]=p1.l; al[2]=p2.l; al[3]=p3.l;
    al[4]=p4.l; al[5]=p5.l; al[6]=p6.l; al[7]=p7.l;
}

// ---------------- gather rows: out[i] = emb[nid[i]] ----------------
__global__ void gather_rows(const float* __restrict__ emb, const int* __restrict__ nid,
                            float* __restrict__ out, int n) {
    int t = blockIdx.x * blockDim.x + threadIdx.x;
    int total = n * (DD / 4);
    if (t >= total) return;
    int row = t / (DD / 4);
    int c4  = t % (DD / 4);
    int srow = nid[row];
    reinterpret_cast<float4*>(out)[(size_t)row * (DD / 4) + c4] =
        reinterpret_cast<const float4*>(emb)[(size_t)srow * (DD / 4) + c4];
}

// ---------------- pack lin_W into MFMA B-fragment order, hi/lo bf16 ----------
// idx(s,n,q,j) = (((s*64+n)*4+q)*8+j);  value = lin_W[k= s*32+q*8+j][n], 0 if k>=1000
__global__ void pack_B(const float* __restrict__ lin_W,
                       short* __restrict__ BH, short* __restrict__ BL) {
    int t = blockIdx.x * blockDim.x + threadIdx.x;
    if (t >= KSTEPS * 64 * 4) return;
    int s = t >> 8, n = (t >> 2) & 63, q = t & 3;
    int base = t * 8;
#pragma unroll
    for (int j = 0; j < 8; ++j) {
        int k = s * 32 + q * 8 + j;
        float v = (k < F_GO) ? lin_W[(size_t)k * 64 + n] : 0.f;
        BfPair p = split_bf(v);
        BH[base + j] = p.h;
        BL[base + j] = p.l;
    }
}

// ---------------- pack all 12 layer weight matrices into B-fragment planes ----
// mat = (l*2+t)*2+m (m: 0=Wl, 1=Wr). Per matrix: 2 ksteps x 64 cols x 4 quads x 8.
__global__ void pack_W(const float* __restrict__ Wl, const float* __restrict__ Wr,
                       short* __restrict__ WH, short* __restrict__ WL_) {
    int t = blockIdx.x * blockDim.x + threadIdx.x;
    if (t >= 12 * 512) return;
    int mat = t >> 9;
    int g = t & 511;
    int s = g >> 8, n = (g >> 2) & 63, q = g & 3;
    int l2t = mat >> 1, m = mat & 1;
    const float* src = (m ? Wr : Wl) + (size_t)l2t * 4096;
    int base = mat * 4096 + g * 8;
#pragma unroll
    for (int j = 0; j < 8; ++j) {
        int k = s * 32 + q * 8 + j;
        BfPair p = split_bf(src[(size_t)k * 64 + n]);
        WH[base + j] = p.h;
        WL_[base + j] = p.l;
    }
}

// ---------------- xg = go_x @ lin_W + lin_b + go_emb[go_nid] ----------------
// No LDS, no barriers. Wave = 16 rows x 64 cols; block = 4 waves = 64 rows.
__global__ __launch_bounds__(256) void lin_go_mfma(const float* __restrict__ go_x,
        const short* __restrict__ BH, const short* __restrict__ BL,
        const float* __restrict__ lin_b, const float* __restrict__ go_emb,
        const int* __restrict__ go_nid, float* __restrict__ out) {
    int tid = threadIdx.x;
    int wave = tid >> 6, lane = tid & 63;
    int ml = lane & 15, q = lane >> 4;
    int row0 = blockIdx.x * 64 + wave * 16;
    const float* arow = go_x + (size_t)(row0 + ml) * F_GO;
    f32x4 acc[4] = {};
    for (int s = 0; s < KSTEPS; ++s) {
        int kb = s * 32 + q * 8;
        int kc = kb > 992 ? 992 : kb;            // clamp tail: B is zero there anyway
        float4 va = *reinterpret_cast<const float4*>(arow + kc);
        float4 vb = *reinterpret_cast<const float4*>(arow + kc + 4);
        bf16x8 ah, al;
        split8(va, vb, ah, al);
#pragma unroll
        for (int nt = 0; nt < 4; ++nt) {
            int off = ((s * 64 + nt * 16 + ml) * 4 + q) * 8;
            bf16x8 bh = *reinterpret_cast<const bf16x8*>(BH + off);
            bf16x8 bl = *reinterpret_cast<const bf16x8*>(BL + off);
            acc[nt] = __builtin_amdgcn_mfma_f32_16x16x32_bf16(ah, bh, acc[nt], 0, 0, 0);
            acc[nt] = __builtin_amdgcn_mfma_f32_16x16x32_bf16(al, bh, acc[nt], 0, 0, 0);
            acc[nt] = __builtin_amdgcn_mfma_f32_16x16x32_bf16(ah, bl, acc[nt], 0, 0, 0);
        }
    }
#pragma unroll
    for (int reg = 0; reg < 4; ++reg) {
        int row = row0 + q * 4 + reg;
        int nid = go_nid[row];
#pragma unroll
        for (int nt = 0; nt < 4; ++nt) {
            int col = nt * 16 + ml;
            out[(size_t)row * 64 + col] = acc[nt][reg] + lin_b[col]
                + go_emb[(size_t)nid * 64 + col];
        }
    }
}

// ---------------- CSR build (both directions fused) ----------------
__global__ void count_both(const int* __restrict__ dst_pg, const int* __restrict__ dst_gp,
                           int* __restrict__ cnt) {
    int t = blockIdx.x * blockDim.x + threadIdx.x;
    if (t < NE)            atomicAdd(&cnt[dst_pg[t]], 1);
    else if (t < 2 * NE)   atomicAdd(&cnt[N_G + dst_gp[t - NE]], 1);
}

__global__ __launch_bounds__(1024) void scan_local(const int* __restrict__ cnt,
        int* __restrict__ loc, int* __restrict__ bsum, int n) {
    __shared__ int sh[1024];
    int i = blockIdx.x * 1024 + threadIdx.x;
    int v = (i < n) ? cnt[i] : 0;
    sh[threadIdx.x] = v;
    __syncthreads();
    for (int off = 1; off < 1024; off <<= 1) {
        int t = (threadIdx.x >= off) ? sh[threadIdx.x - off] : 0;
        __syncthreads();
        sh[threadIdx.x] += t;
        __syncthreads();
    }
    if (i < n) loc[i] = sh[threadIdx.x] - v;
    if (threadIdx.x == 1023) bsum[blockIdx.x] = sh[1023];
}

__global__ __launch_bounds__(1024) void scan_bsum(int* __restrict__ bsum, int nb) {
    __shared__ int sh[1024];
    int v = (threadIdx.x < nb) ? bsum[threadIdx.x] : 0;
    sh[threadIdx.x] = v;
    __syncthreads();
    for (int off = 1; off < 1024; off <<= 1) {
        int t = (threadIdx.x >= off) ? sh[threadIdx.x - off] : 0;
        __syncthreads();
        sh[threadIdx.x] += t;
        __syncthreads();
    }
    if (threadIdx.x < nb) bsum[threadIdx.x] = sh[threadIdx.x] - v;
}

// combined scan -> both rowptr/cursor arrays (p side offset by -NE)
__global__ void scan_add2(const int* __restrict__ loc, const int* __restrict__ bsum,
                          int* __restrict__ rowptr_g, int* __restrict__ cursor_g,
                          int* __restrict__ rowptr_p, int* __restrict__ cursor_p) {
    int i = blockIdx.x * blockDim.x + threadIdx.x;
    int n = N_G + N_P;
    if (i < n) {
        int v = loc[i] + bsum[i >> 10];
        if (i < N_G) { rowptr_g[i] = v; cursor_g[i] = v; }
        else         { rowptr_p[i - N_G] = v - NE; cursor_p[i - N_G] = v - NE; }
    } else if (i == n) {
        rowptr_g[N_G] = NE;
        rowptr_p[N_P] = NE;
    }
}

__global__ void fill_both(const int* __restrict__ src_pg, const int* __restrict__ dst_pg,
                          const int* __restrict__ src_gp, const int* __restrict__ dst_gp,
                          int* __restrict__ cursor_g, int* __restrict__ csr_g,
                          int* __restrict__ cursor_p, int* __restrict__ csr_p) {
    int t = blockIdx.x * blockDim.x + threadIdx.x;
    if (t < NE) {
        int slot = atomicAdd(&cursor_g[dst_pg[t]], 1);
        csr_g[slot] = src_pg[t];
    } else if (t < 2 * NE) {
        int e = t - NE;
        int slot = atomicAdd(&cursor_p[dst_gp[e]], 1);
        csr_p[slot] = src_gp[e];
    }
}

// ---------------- fused aggregation: both directions in one grid --------------
// wave per dst row; quarter-wave per edge slot; 16 lanes x float4 = 256B row.
// Unroll 4 -> up to 16 row-gathers in flight per wave.
__global__ void aggregate_fused(const float* __restrict__ xp, const int* __restrict__ rowptr_g,
                                const int* __restrict__ csr_g, float* __restrict__ sg,
                                const float* __restrict__ xg, const int* __restrict__ rowptr_p,
                                const int* __restrict__ csr_p, float* __restrict__ sp) {
    int b = blockIdx.x;
    const float* x; const int* rp; const int* cs; float* o; int row, n;
    if (b < ABG) { x = xp; rp = rowptr_g; cs = csr_g; o = sg; n = N_G; row = b * 4 + (threadIdx.x >> 6); }
    else         { x = xg; rp = rowptr_p; cs = csr_p; o = sp; n = N_P; row = (b - ABG) * 4 + (threadIdx.x >> 6); }
    if (row >= n) return;
    int lane = threadIdx.x & 63;
    int qg   = lane >> 4;
    int l16  = lane & 15;
    int s = rp[row], e = rp[row + 1];
    const float4* x4 = reinterpret_cast<const float4*>(x);
    float4 a0 = make_float4(0.f, 0.f, 0.f, 0.f);
    float4 a1 = make_float4(0.f, 0.f, 0.f, 0.f);
    float4 a2 = make_float4(0.f, 0.f, 0.f, 0.f);
    float4 a3 = make_float4(0.f, 0.f, 0.f, 0.f);
    int i = s + qg;
    for (; i + 12 < e; i += 16) {
        int s0 = cs[i], s1 = cs[i + 4], s2 = cs[i + 8], s3 = cs[i + 12];
        float4 v0 = x4[(size_t)s0 * 16 + l16];
        float4 v1 = x4[(size_t)s1 * 16 + l16];
        float4 v2 = x4[(size_t)s2 * 16 + l16];
        float4 v3 = x4[(size_t)s3 * 16 + l16];
        a0.x += v0.x; a0.y += v0.y; a0.z += v0.z; a0.w += v0.w;
        a1.x += v1.x; a1.y += v1.y; a1.z += v1.z; a1.w += v1.w;
        a2.x += v2.x; a2.y += v2.y; a2.z += v2.z; a2.w += v2.w;
        a3.x += v3.x; a3.y += v3.y; a3.z += v3.z; a3.w += v3.w;
    }
    for (; i < e; i += 4) {
        int s0 = cs[i];
        float4 v0 = x4[(size_t)s0 * 16 + l16];
        a0.x += v0.x; a0.y += v0.y; a0.z += v0.z; a0.w += v0.w;
    }
    a0.x += a1.x + a2.x + a3.x;
    a0.y += a1.y + a2.y + a3.y;
    a0.z += a1.z + a2.z + a3.z;
    a0.w += a1.w + a2.w + a3.w;
    a0.x += __shfl_xor(a0.x, 16); a0.y += __shfl_xor(a0.y, 16);
    a0.z += __shfl_xor(a0.z, 16); a0.w += __shfl_xor(a0.w, 16);
    a0.x += __shfl_xor(a0.x, 32); a0.y += __shfl_xor(a0.y, 32);
    a0.z += __shfl_xor(a0.z, 32); a0.w += __shfl_xor(a0.w, 32);
    if (qg == 0) {
        float inv = (e > s) ? 1.0f / (float)(e - s) : 0.0f;
        float4 r = make_float4(a0.x * inv, a0.y * inv, a0.z * inv, a0.w * inv);
        reinterpret_cast<float4*>(o)[(size_t)row * 16 + l16] = r;
    }
}

// ---------------- fused node update: both sides, LDS-free, bf16x3 MFMA --------
// out = agg@Wl + bias + x@Wr, optional ReLU; in-place into agg buffer.
// Wave = 16 rows x 64 cols. Per-wave rows disjoint -> in-place safe without barriers.
__global__ __launch_bounds__(256) void update_fused(
        float* sg, const float* __restrict__ xg,
        float* sp, const float* __restrict__ xp,
        const short* __restrict__ WH, const short* __restrict__ WL_,
        const float* __restrict__ bl, int l, int relu) {
    int b = blockIdx.x;
    const float* aggp; const float* xx; float* o; int n, t, row0;
    if (b < NBG) { aggp = sg; xx = xg; o = sg; n = N_G; t = 0; row0 = b * 64; }
    else         { aggp = sp; xx = xp; o = sp; n = N_P; t = 1; row0 = (b - NBG) * 64; }
    int tid = threadIdx.x;
    int wave = tid >> 6, lane = tid & 63;
    int ml = lane & 15, q = lane >> 4;
    int rowA = row0 + wave * 16 + ml;
    if (rowA > n - 1) rowA = n - 1;          // tail clamp stays within this block's rows
    const float* bias = bl + (size_t)(l * 2 + t) * 64;
    f32x4 acc[4] = {};
#pragma unroll
    for (int m = 0; m < 2; ++m) {
        const float* X = m ? xx : aggp;
        int mat = (l * 2 + t) * 2 + m;
        const float* arow = X + (size_t)rowA * 64;
#pragma unroll
        for (int s = 0; s < 2; ++s) {
            int kb = s * 32 + q * 8;
            float4 va = *reinterpret_cast<const float4*>(arow + kb);
            float4 vb = *reinterpret_cast<const float4*>(arow + kb + 4);
            bf16x8 ah, al;
            split8(va, vb, ah, al);
#pragma unroll
            for (int nt = 0; nt < 4; ++nt) {
                int off = mat * 4096 + ((s * 64 + nt * 16 + ml) * 4 + q) * 8;
                bf16x8 bh = *reinterpret_cast<const bf16x8*>(WH + off);
                bf16x8 b2 = *reinterpret_cast<const bf16x8*>(WL_ + off);
                acc[nt] = __builtin_amdgcn_mfma_f32_16x16x32_bf16(ah, bh, acc[nt], 0, 0, 0);
                acc[nt] = __builtin_amdgcn_mfma_f32_16x16x32_bf16(al, bh, acc[nt], 0, 0, 0);
                acc[nt] = __builtin_amdgcn_mfma_f32_16x16x32_bf16(ah, b2, acc[nt], 0, 0, 0);
            }
        }
    }
#pragma unroll
    for (int reg = 0; reg < 4; ++reg) {
        int row = row0 + wave * 16 + q * 4 + reg;
        if (row >= n) continue;
#pragma unroll
        for (int nt = 0; nt < 4; ++nt) {
            int col = nt * 16 + ml;
            float v = acc[nt][reg] + bias[col];
            if (relu) v = fmaxf(v, 0.0f);
            o[(size_t)row * 64 + col] = v;
        }
    }
}

// ---------------- classifier ----------------
__global__ void classify(const float* __restrict__ xp, const float* __restrict__ xg,
                         const int* __restrict__ ls, const int* __restrict__ ld,
                         float* __restrict__ out, int nE) {
    int t = blockIdx.x * blockDim.x + threadIdx.x;
    int e = t >> 4;
    int l16 = t & 15;
    if (e >= nE) return;
    int s = ls[e], d = ld[e];
    float4 a = reinterpret_cast<const float4*>(xp)[(size_t)s * 16 + l16];
    float4 b = reinterpret_cast<const float4*>(xg)[(size_t)d * 16 + l16];
    float v = a.x * b.x + a.y * b.y + a.z * b.z + a.w * b.w;
    v += __shfl_xor(v, 8);
    v += __shfl_xor(v, 4);
    v += __shfl_xor(v, 2);
    v += __shfl_xor(v, 1);
    if (l16 == 0) out[e] = v;
}

extern "C" void kernel_launch(void* const* d_in, const int* in_sizes, int n_in,
                              void* d_out, int out_size, void* d_ws, size_t ws_size,
                              hipStream_t stream) {
    const float* go_x        = (const float*)d_in[0];
    const float* protein_emb = (const float*)d_in[1];
    const float* go_emb      = (const float*)d_in[2];
    const float* lin_W       = (const float*)d_in[3];
    const float* lin_b       = (const float*)d_in[4];
    const float* Wl          = (const float*)d_in[5];
    const float* bl          = (const float*)d_in[6];
    const float* Wr          = (const float*)d_in[7];
    const int* protein_nid   = (const int*)d_in[8];
    const int* go_nid        = (const int*)d_in[9];
    const int* src_pg        = (const int*)d_in[10];
    const int* dst_pg        = (const int*)d_in[11];
    const int* src_gp        = (const int*)d_in[12];
    const int* dst_gp        = (const int*)d_in[13];
    const int* label_src     = (const int*)d_in[14];
    const int* label_dst     = (const int*)d_in[15];
    float* out = (float*)d_out;

    float* ws = (float*)d_ws;
    float* p0 = ws;
    float* p1 = p0 + (size_t)N_P * 64;
    float* g0 = p1 + (size_t)N_P * 64;
    float* g1 = g0 + (size_t)N_G * 64;
    int* ib = (int*)(g1 + (size_t)N_G * 64);
    int* rowptr_g = ib;                 ib += N_G + 1;
    int* cursor_g = ib;                 ib += N_G + 1;
    int* rowptr_p = ib;                 ib += N_P + 1;
    int* cursor_p = ib;                 ib += N_P + 1;
    int* cnt_i    = ib;                 ib += N_G + N_P;     // combined counts
    int* loc      = ib;                 ib += N_G + N_P;     // combined scan
    int* bsum     = ib;                 ib += 1024;
    int* csr_g    = ib;                 ib += NE;
    int* csr_p    = ib;                 ib += NE;
    short* BfragH = (short*)ib;         // 65536 shorts
    short* BfragL = BfragH + KSTEPS * 64 * 4 * 8;
    short* WfragH = BfragL + KSTEPS * 64 * 4 * 8;   // 12*4096 shorts
    short* WfragL = WfragH + 12 * 4096;

    // ---- input embeddings + weight packing ----
    gather_rows<<<(N_P * (DD / 4) + 255) / 256, 256, 0, stream>>>(protein_emb, protein_nid, p0, N_P);
    pack_B<<<(KSTEPS * 64 * 4 + 255) / 256, 256, 0, stream>>>(lin_W, BfragH, BfragL);
    pack_W<<<(12 * 512 + 255) / 256, 256, 0, stream>>>(Wl, Wr, WfragH, WfragL);
    lin_go_mfma<<<N_G / 64, 256, 0, stream>>>(go_x, BfragH, BfragL, lin_b, go_emb, go_nid, g0);

    // ---- CSR build (both directions, fused) ----
    hipMemsetAsync(cnt_i, 0, (size_t)(N_G + N_P) * sizeof(int), stream);
    count_both<<<(2 * NE + 255) / 256, 256, 0, stream>>>(dst_pg, dst_gp, cnt_i);
    int n_comb = N_G + N_P;
    scan_local<<<(n_comb + 1023) / 1024, 1024, 0, stream>>>(cnt_i, loc, bsum, n_comb);
    scan_bsum<<<1, 1024, 0, stream>>>(bsum, (n_comb + 1023) / 1024);
    scan_add2<<<(n_comb + 1 + 255) / 256, 256, 0, stream>>>(loc, bsum, rowptr_g, cursor_g, rowptr_p, cursor_p);
    fill_both<<<(2 * NE + 255) / 256, 256, 0, stream>>>(src_pg, dst_pg, src_gp, dst_gp,
                                                        cursor_g, csr_g, cursor_p, csr_p);

    // ---- layers ----
    float* xp = p0; float* xg = g0; float* sp = p1; float* sg = g1;
    for (int l = 0; l < 3; ++l) {
        aggregate_fused<<<ABG + ABP, 256, 0, stream>>>(xp, rowptr_g, csr_g, sg,
                                                       xg, rowptr_p, csr_p, sp);
        int relu = (l < 2) ? 1 : 0;
        update_fused<<<NBG + NBP, 256, 0, stream>>>(sg, xg, sp, xp, WfragH, WfragL, bl, l, relu);
        float* t;
        t = xp; xp = sp; sp = t;
        t = xg; xg = sg; sg = t;
    }
    classify<<<(E_LBL * 16 + 255) / 256, 256, 0, stream>>>(xp, xg, label_src, label_dst, out, E_LBL);
}